// Round 8
// baseline (851.005 us; speedup 1.0000x reference)
//
#include <hip/hip_runtime.h>

// Problem constants
#define BB 256
#define NN 5
#define EPSF 1e-8f
#define NBLK 512
#define TPB 512
#define FANIN 32              // blocks cooperating per b (one oc-group each)
#define NSETS (NBLK / FANIN)  // 16 concurrent b's
#define NIT (BB / NSETS)      // 16 iterations per block

typedef float f4 __attribute__((ext_vector_type(4)));

// One-read cooperative kernel, 512 blocks x 512 threads (2 blocks/CU).
// Set s = contiguous bids [32s, 32s+32) -> 4 blocks per XCD (RR), correlated
// progress. Block j of a set owns oc-group j (channels 20j..20j+19) of all 5
// shots of b = it*16 + s. Per iteration:
//   A: 500 threads load one 2-row strip (5 f4) each -> regs -> LDS xw (40KB)
//   pool: strips -> psum -> 125 cells -> feats -> 11 partials (wave 0)
//   post partials + release counter; PREFETCH next chunk into regs;
//   thread0 spins to FANIN; 32 lanes gather partials, reduce -> sim
//   C: out strip f4 = sum_n sim[n]*xw[n*500+v], NT store (coalesced 8KB run)
__global__ __launch_bounds__(TPB, 4) void k_coop(const float* __restrict__ x,
                                                 float* __restrict__ out,
                                                 float* __restrict__ g_part, // [BB][FANIN][11]
                                                 int* __restrict__ g_cnt) {  // [BB]
    __shared__ f4 xw[2500];            // 40000 B: [n][strip r][5] f4
    __shared__ float psum[500][6];     // 12000 B: row-pair ow-sums (padded)
    __shared__ float feats[NN][25];
    __shared__ float s_sim[NN];
    const int tid = threadIdx.x;
    const int set = blockIdx.x / FANIN;   // 0..15
    const int j   = blockIdx.x % FANIN;   // oc-group 0..31
    const int n   = tid / 100;            // shot (for tid < 500)
    const int rr  = tid - n * 100;        // strip within shot: cl*5 + oh

    // Prologue: load chunk for it=0 into registers.
    f4 r0 = {}, r1 = {}, r2 = {}, r3 = {}, r4 = {};
    if (tid < 500) {
        const f4* __restrict__ src = reinterpret_cast<const f4*>(x) +
            ((size_t)(set * NN + n)) * 16000 + 500 * (size_t)j + 5 * rr;
        r0 = src[0]; r1 = src[1]; r2 = src[2]; r3 = src[3]; r4 = src[4];
    }

    for (int it = 0; it < NIT; ++it) {
        const int b = it * NSETS + set;

        // ---- stage regs -> LDS; compute row-pair ow-sums ----
        if (tid < 500) {
            const int base = n * 500 + rr * 5;
            xw[base + 0] = r0; xw[base + 1] = r1; xw[base + 2] = r2;
            xw[base + 3] = r3; xw[base + 4] = r4;
            float w[20];
            *(f4*)&w[0] = r0; *(f4*)&w[4] = r1; *(f4*)&w[8] = r2;
            *(f4*)&w[12] = r3; *(f4*)&w[16] = r4;
            #pragma unroll
            for (int ow = 0; ow < 5; ++ow)
                psum[tid][ow] = (w[2*ow] + w[2*ow+1]) + (w[10+2*ow] + w[11+2*ow]);
        }
        __syncthreads();

        // ---- pool: 125 (n, oh, ow) cells, 20 channels each ----
        if (tid < 125) {
            const int nn = tid / 25, c25 = tid - nn * 25;
            const int oh = c25 / 5, ow = c25 - oh * 5;
            float s = 0.f;
            #pragma unroll
            for (int cc = 0; cc < 20; ++cc)
                s += psum[nn * 100 + cc * 5 + oh][ow];
            feats[nn][c25] = s * (1.f / 80.f);
        }
        __syncthreads();

        // ---- local partials over the block's 25 d-dims (wave 0) ----
        if (tid < 64) {
            float part[11];
            #pragma unroll
            for (int k = 0; k < 11; ++k) part[k] = 0.f;
            if (tid < 25) {
                float f[NN], p = 0.f;
                #pragma unroll
                for (int q = 0; q < NN; ++q) { f[q] = feats[q][tid]; p += f[q]; }
                #pragma unroll
                for (int q = 0; q < NN; ++q) { part[q] = f[q] * p; part[5+q] = f[q] * f[q]; }
                part[10] = p * p;
            }
            #pragma unroll
            for (int off = 32; off >= 1; off >>= 1)
                #pragma unroll
                for (int k = 0; k < 11; ++k)
                    part[k] += __shfl_down(part[k], off, 64);
            if (tid == 0) {
                #pragma unroll
                for (int k = 0; k < 11; ++k)
                    __hip_atomic_store(&g_part[((size_t)b * FANIN + j) * 11 + k], part[k],
                                       __ATOMIC_RELAXED, __HIP_MEMORY_SCOPE_AGENT);
                __hip_atomic_fetch_add(&g_cnt[b], 1,
                                       __ATOMIC_RELEASE, __HIP_MEMORY_SCOPE_AGENT);
            }
        }

        // ---- prefetch next chunk into regs (hides under the spin) ----
        if (it + 1 < NIT && tid < 500) {
            const int b2 = (it + 1) * NSETS + set;
            const f4* __restrict__ src = reinterpret_cast<const f4*>(x) +
                ((size_t)(b2 * NN + n)) * 16000 + 500 * (size_t)j + 5 * rr;
            r0 = src[0]; r1 = src[1]; r2 = src[2]; r3 = src[3]; r4 = src[4];
        }

        // ---- spin to fan-in (thread 0 only; other block on CU keeps working)
        if (tid == 0) {
            while (__hip_atomic_load(&g_cnt[b],
                                     __ATOMIC_ACQUIRE, __HIP_MEMORY_SCOPE_AGENT) < FANIN)
                __builtin_amdgcn_s_sleep(2);
        }
        __syncthreads();

        // ---- 32-lane parallel gather of partials; reduce; sim ----
        if (tid < 64) {
            float t[11];
            #pragma unroll
            for (int k = 0; k < 11; ++k) t[k] = 0.f;
            if (tid < 32) {
                #pragma unroll
                for (int k = 0; k < 11; ++k)
                    t[k] = __hip_atomic_load(&g_part[((size_t)b * FANIN + tid) * 11 + k],
                                             __ATOMIC_RELAXED, __HIP_MEMORY_SCOPE_AGENT);
            }
            #pragma unroll
            for (int off = 32; off >= 1; off >>= 1)
                #pragma unroll
                for (int k = 0; k < 11; ++k)
                    t[k] += __shfl_down(t[k], off, 64);
            if (tid == 0) {
                const float nb = sqrtf(t[10]);
                #pragma unroll
                for (int q = 0; q < NN; ++q)
                    s_sim[q] = t[q] / fmaxf(sqrtf(t[5+q]) * nb, EPSF);
            }
        }
        __syncthreads();

        // ---- Phase C: out chunk from LDS, coalesced NT store ----
        if (tid < 500) {
            const f4 o = s_sim[0] * xw[tid]
                       + s_sim[1] * xw[500 + tid]
                       + s_sim[2] * xw[1000 + tid]
                       + s_sim[3] * xw[1500 + tid]
                       + s_sim[4] * xw[2000 + tid];
            __builtin_nontemporal_store(
                o, reinterpret_cast<f4*>(out) + (size_t)b * 16000 + 500 * (size_t)j + tid);
        }
        __syncthreads();   // xw/psum reused next iteration
    }
}

extern "C" void kernel_launch(void* const* d_in, const int* in_sizes, int n_in,
                              void* d_out, int out_size, void* d_ws, size_t ws_size,
                              hipStream_t stream) {
    const float* x = (const float*)d_in[0];
    float* out = (float*)d_out;
    // ws layout: g_cnt [256 ints, 1KB] | g_part [256*32*11 floats]
    int* g_cnt = (int*)d_ws;
    float* g_part = (float*)((char*)d_ws + 1024);
    hipMemsetAsync(d_ws, 0,
                   1024 + (size_t)BB * FANIN * 11 * sizeof(float), stream);
    k_coop<<<NBLK, TPB, 0, stream>>>(x, out, g_part, g_cnt);
}

// Round 9
// 125.115 us; speedup vs baseline: 6.8018x; 6.8018x over previous
//
#include <hip/hip_runtime.h>

// Problem constants
#define BB 256
#define NN 5
#define CHW 64000            // C*H*W floats per (b,n)
#define DD 800               // 32*5*5 pooled dims
#define EPSF 1e-8f

typedef float f4 __attribute__((ext_vector_type(4)));

// ---------------- Kernel A: pool, one thread per (b,n,oc,oh) cell-row ----
// 256*5*32*5 = 204800 threads. Each reads rows 2oh,2oh+1 of its 20 channels
// (20 x 5 float4, 400B-contiguous chunks) and writes 5 pooled floats.
// Streams b = 0..255 in bid order -> L3 ends holding the TAIL (b >= ~56).
__global__ __launch_bounds__(256) void k_pool(const float* __restrict__ x,
                                              float* __restrict__ feats) {
    const int g = blockIdx.x * 256 + threadIdx.x;   // 0..204799
    const int b = g / 800;
    const int r = g - b * 800;
    const int n = r / 160;
    const int q = r - n * 160;
    const int oc = q / 5;
    const int oh = q - oc * 5;
    const f4* __restrict__ p = reinterpret_cast<const f4*>(x) +
                               ((size_t)b * NN + n) * (CHW / 4) + oc * 500 + oh * 5;
    float s0 = 0.f, s1 = 0.f, s2 = 0.f, s3 = 0.f, s4 = 0.f;
    #pragma unroll 4
    for (int cc = 0; cc < 20; ++cc) {
        const f4 v0 = p[cc * 25 + 0];   // h0 w0..3
        const f4 v1 = p[cc * 25 + 1];   // h0 w4..7
        const f4 v2 = p[cc * 25 + 2];   // h0 w8,9 | h1 w0,1
        const f4 v3 = p[cc * 25 + 3];   // h1 w2..5
        const f4 v4 = p[cc * 25 + 4];   // h1 w6..9
        s0 += (v0.x + v0.y) + (v2.z + v2.w);
        s1 += (v0.z + v0.w) + (v3.x + v3.y);
        s2 += (v1.x + v1.y) + (v3.z + v3.w);
        s3 += (v1.z + v1.w) + (v4.x + v4.y);
        s4 += (v2.x + v2.y) + (v4.z + v4.w);
    }
    float* fp = feats + ((size_t)b * NN + n) * DD + oc * 25 + oh * 5;
    fp[0] = s0 * (1.f / 80.f);
    fp[1] = s1 * (1.f / 80.f);
    fp[2] = s2 * (1.f / 80.f);
    fp[3] = s3 * (1.f / 80.f);
    fp[4] = s4 * (1.f / 80.f);
}

// ---------------- Kernel B: cosine sims, one wave per b ----------------
__global__ __launch_bounds__(64) void k_sim(const float* __restrict__ feats,
                                            float* __restrict__ sim) {
    const int b = blockIdx.x;
    const int lane = threadIdx.x;
    const float* __restrict__ fb = feats + (size_t)b * NN * DD;
    float dot[NN] = {0.f, 0.f, 0.f, 0.f, 0.f};
    float na2[NN] = {0.f, 0.f, 0.f, 0.f, 0.f};
    float nb2 = 0.f;
    for (int d = lane; d < DD; d += 64) {
        float f[NN];
        float p = 0.f;
        #pragma unroll
        for (int n = 0; n < NN; ++n) { f[n] = fb[n * DD + d]; p += f[n]; }
        #pragma unroll
        for (int n = 0; n < NN; ++n) {
            dot[n] += f[n] * p;
            na2[n] += f[n] * f[n];
        }
        nb2 += p * p;
    }
    #pragma unroll
    for (int off = 32; off >= 1; off >>= 1) {
        #pragma unroll
        for (int n = 0; n < NN; ++n) {
            dot[n] += __shfl_down(dot[n], off, 64);
            na2[n] += __shfl_down(na2[n], off, 64);
        }
        nb2 += __shfl_down(nb2, off, 64);
    }
    if (lane == 0) {
        const float nb = sqrtf(nb2);
        #pragma unroll
        for (int n = 0; n < NN; ++n) {
            const float denom = fmaxf(sqrtf(na2[n]) * nb, EPSF);
            sim[b * NN + n] = dot[n] / denom;
        }
    }
}

// ---------------- Kernel C: out[b] = sum_n sim[b,n] * x[b,n] -----------
// REVERSE b-order (early bids -> b=255, the L3-freshest slabs) with REGULAR
// loads (hits must go through the cache; NT loads bypass the MALL lookup).
// Misses (b < ~56) come last, when resident data is already consumed.
// NT stores: out is write-once, don't allocate.
__global__ __launch_bounds__(256) void k_out(const float* __restrict__ x,
                                             const float* __restrict__ sim,
                                             float* __restrict__ out) {
    const int i = blockIdx.x * 256 + threadIdx.x;   // 0 .. BB*16000-1
    const int b = (BB - 1) - i / 16000;             // descending b
    const int r = i - ((BB - 1) - b) * 16000;
    const f4* __restrict__ xp =
        reinterpret_cast<const f4*>(x) + (size_t)b * (NN * 16000) + r;
    const float s0 = sim[b * NN + 0];
    const float s1 = sim[b * NN + 1];
    const float s2 = sim[b * NN + 2];
    const float s3 = sim[b * NN + 3];
    const float s4 = sim[b * NN + 4];
    const f4 a0 = xp[0 * 16000];
    const f4 a1 = xp[1 * 16000];
    const f4 a2 = xp[2 * 16000];
    const f4 a3 = xp[3 * 16000];
    const f4 a4 = xp[4 * 16000];
    f4 o = s0 * a0 + s1 * a1 + s2 * a2 + s3 * a3 + s4 * a4;
    __builtin_nontemporal_store(
        o, reinterpret_cast<f4*>(out) + (size_t)b * 16000 + r);
}

extern "C" void kernel_launch(void* const* d_in, const int* in_sizes, int n_in,
                              void* d_out, int out_size, void* d_ws, size_t ws_size,
                              hipStream_t stream) {
    const float* x = (const float*)d_in[0];
    float* out = (float*)d_out;
    // workspace layout: feats [B*N*800] f32, then sim [B*N] f32
    float* feats = (float*)d_ws;
    float* sim = feats + (size_t)BB * NN * DD;

    k_pool<<<BB * NN * 160 / 256, 256, 0, stream>>>(x, feats);   // 800 blocks
    k_sim<<<BB, 64, 0, stream>>>(feats, sim);
    k_out<<<BB * 16000 / 256, 256, 0, stream>>>(x, sim, out);    // 16000 blocks
}